// Round 1
// 141.386 us; speedup vs baseline: 1.1161x; 1.1161x over previous
//
#include <hip/hip_runtime.h>
#include <math.h>

#define N_NODES 50000
#define N_EDGES 800000
#define N_CLUST 5000
#define DIM     128
#define NOUT    40
#define SLOTS   64          // max in-degree kept; Poisson(16) tail beyond 64 ~1e-19
#define CSLOT   64          // max cluster size kept; multinomial(50k,5k) max ~25

// bucketized edge ingest
#define NBKT    391                          // ceil(50000/128) dst-buckets of 128 nodes
#define BCAP    2560                         // per-bucket capacity (lambda=2048, +11 sigma)
#define GB_STR  16                           // gbcnt stride (1 counter per 64B line)
#define BUCKB   250                          // bucketize blocks, 3200 edges each
#define EPB4    800                          // int4 per bucketize block

// block layout in fused_A: [zgemm ZB) [inv INVB) [bucketize BUCKB)
#define ZB     782                           // 782*4 = 3128 waves, 1 tile each >= 3125
#define INVB   50
#define GRID_A (ZB + INVB + BUCKB)           // 1082

typedef __attribute__((ext_vector_type(8))) short short8;
typedef __attribute__((ext_vector_type(4))) float fvec4;
typedef __attribute__((ext_vector_type(4))) int ivec4;

// ---------- bf16 helpers (RNE) ----------
__device__ __forceinline__ short bf16r(float v) {
    unsigned u = __float_as_uint(v);
    u = (u + 0x7FFFu + ((u >> 16) & 1u)) >> 16;
    return (short)u;
}
__device__ __forceinline__ unsigned pack_bf16x2(float a, float b) {
    unsigned ua = __float_as_uint(a);
    unsigned ub = __float_as_uint(b);
    ua = (ua + 0x7FFFu + ((ua >> 16) & 1u)) >> 16;
    ub = (ub + 0x7FFFu + ((ub >> 16) & 1u)) >> 16;
    return ua | (ub << 16);
}
__device__ __forceinline__ float2 unpack_bf16x2(unsigned v) {
    float2 r;
    r.x = __uint_as_float(v << 16);
    r.y = __uint_as_float(v & 0xFFFF0000u);
    return r;
}
__device__ __forceinline__ float4 unpack_bf16x4(uint2 v) {
    float4 r;
    r.x = __uint_as_float(v.x << 16);
    r.y = __uint_as_float(v.x & 0xFFFF0000u);
    r.z = __uint_as_float(v.y << 16);
    r.w = __uint_as_float(v.y & 0xFFFF0000u);
    return r;
}

// ---------- fused A: zgemm (0..781) | inv (782..831) | bucketize (832..1081) ----------
__global__ __launch_bounds__(256) void fused_A(const float* __restrict__ x,
                                               const int* __restrict__ esrc,
                                               const int* __restrict__ edst,
                                               const int* __restrict__ cidx,
                                               const float* __restrict__ W,
                                               int* __restrict__ ccnt,
                                               unsigned short* __restrict__ zs,
                                               unsigned short* __restrict__ cinv,
                                               int* __restrict__ gbcnt,
                                               unsigned* __restrict__ gbuck) {
    __shared__ int bcnt[NBKT];
    __shared__ int bbase[NBKT];
    int lane = threadIdx.x & 63;
    int wv = threadIdx.x >> 6;

    if (blockIdx.x < ZB) {
        // ---- zgemm UNSCALED: zs[n][o] = bf16( dot(x[n], W[o]) ), 1 tile/wave ----
        int gw = blockIdx.x * 4 + wv;                 // 0..3127
        if (gw >= N_NODES / 16) return;
        int q = lane >> 4, r16 = lane & 15;

        short8 bfr[3][4];
        #pragma unroll
        for (int t = 0; t < 3; t++) {
            int o = t * 16 + r16;
            #pragma unroll
            for (int s = 0; s < 4; s++) {
                short8 f = {0, 0, 0, 0, 0, 0, 0, 0};
                if (o < NOUT) {
                    const float* wp = W + o * DIM + s * 32 + q * 8;
                    float4 w0 = *(const float4*)wp;
                    float4 w1 = *(const float4*)(wp + 4);
                    f[0] = bf16r(w0.x); f[1] = bf16r(w0.y);
                    f[2] = bf16r(w0.z); f[3] = bf16r(w0.w);
                    f[4] = bf16r(w1.x); f[5] = bf16r(w1.y);
                    f[6] = bf16r(w1.z); f[7] = bf16r(w1.w);
                }
                bfr[t][s] = f;
            }
        }

        int tile = gw;
        int node = tile * 16 + r16;
        short8 af[4];
        #pragma unroll
        for (int s = 0; s < 4; s++) {
            const fvec4* xp = (const fvec4*)(x + (size_t)node * DIM + s * 32 + q * 8);
            fvec4 a0 = *xp;                       // normal load: x is L3-resident
            fvec4 a1 = *(xp + 1);
            short8 f;
            f[0] = bf16r(a0.x); f[1] = bf16r(a0.y);
            f[2] = bf16r(a0.z); f[3] = bf16r(a0.w);
            f[4] = bf16r(a1.x); f[5] = bf16r(a1.y);
            f[6] = bf16r(a1.z); f[7] = bf16r(a1.w);
            af[s] = f;
        }

        fvec4 acc0 = {0, 0, 0, 0}, acc1 = {0, 0, 0, 0}, acc2 = {0, 0, 0, 0};
        #pragma unroll
        for (int s = 0; s < 4; s++) {
            acc0 = __builtin_amdgcn_mfma_f32_16x16x32_bf16(af[s], bfr[0][s], acc0, 0, 0, 0);
            acc1 = __builtin_amdgcn_mfma_f32_16x16x32_bf16(af[s], bfr[1][s], acc1, 0, 0, 0);
            acc2 = __builtin_amdgcn_mfma_f32_16x16x32_bf16(af[s], bfr[2][s], acc2, 0, 0, 0);
        }

        #pragma unroll
        for (int r = 0; r < 4; r++) {
            int nd = tile * 16 + q * 4 + r;
            unsigned short* zrow = zs + (size_t)nd * NOUT;
            __builtin_nontemporal_store((unsigned short)bf16r(acc0[r]), &zrow[r16]);
            __builtin_nontemporal_store((unsigned short)bf16r(acc1[r]), &zrow[16 + r16]);
            if (r16 < 8)
                __builtin_nontemporal_store((unsigned short)bf16r(acc2[r]), &zrow[32 + r16]);
        }
    } else if (blockIdx.x < ZB + INVB) {
        // ---- inverse cluster list: cinv[c][pos] = node ----
        int t0 = (blockIdx.x - ZB) * 256 + threadIdx.x;
        for (int i = t0; i < N_NODES; i += INVB * 256) {
            int c = cidx[i];
            int pos = atomicAdd(&ccnt[c], 1);
            if (pos < CSLOT) cinv[c * CSLOT + pos] = (unsigned short)i;
        }
    } else {
        // ---- bucketize: per-block LDS histogram -> 1 global atomic per (block,bucket) ----
        int fb = blockIdx.x - ZB - INVB;             // 0..249
        const ivec4* src4 = (const ivec4*)esrc;
        const ivec4* dst4 = (const ivec4*)edst;
        int q0 = fb * EPB4;

        for (int i = threadIdx.x; i < NBKT; i += 256) bcnt[i] = 0;
        __syncthreads();

        // scan 1: histogram dst>>7 into LDS
        for (int i = threadIdx.x; i < EPB4; i += 256) {
            ivec4 d4 = dst4[q0 + i];
            atomicAdd(&bcnt[d4.x >> 7], 1);
            atomicAdd(&bcnt[d4.y >> 7], 1);
            atomicAdd(&bcnt[d4.z >> 7], 1);
            atomicAdd(&bcnt[d4.w >> 7], 1);
        }
        __syncthreads();

        // reserve global ranges (one device atomic per non-empty bucket)
        for (int bk = threadIdx.x; bk < NBKT; bk += 256) {
            int c = bcnt[bk];
            bbase[bk] = c ? atomicAdd(&gbcnt[bk * GB_STR], c) : 0;
        }
        __syncthreads();
        for (int i = threadIdx.x; i < NBKT; i += 256) bcnt[i] = 0;
        __syncthreads();

        // scan 2: write packed (dst<<16)|src into reserved ranges
        for (int i = threadIdx.x; i < EPB4; i += 256) {
            ivec4 d4 = dst4[q0 + i];
            ivec4 s4 = src4[q0 + i];
            {
                int bk = d4.x >> 7; int idx = atomicAdd(&bcnt[bk], 1);
                unsigned p = (unsigned)(bbase[bk] + idx);
                if (p < BCAP) gbuck[(size_t)bk * BCAP + p] = ((unsigned)d4.x << 16) | (unsigned)s4.x;
            }
            {
                int bk = d4.y >> 7; int idx = atomicAdd(&bcnt[bk], 1);
                unsigned p = (unsigned)(bbase[bk] + idx);
                if (p < BCAP) gbuck[(size_t)bk * BCAP + p] = ((unsigned)d4.y << 16) | (unsigned)s4.y;
            }
            {
                int bk = d4.z >> 7; int idx = atomicAdd(&bcnt[bk], 1);
                unsigned p = (unsigned)(bbase[bk] + idx);
                if (p < BCAP) gbuck[(size_t)bk * BCAP + p] = ((unsigned)d4.z << 16) | (unsigned)s4.z;
            }
            {
                int bk = d4.w >> 7; int idx = atomicAdd(&bcnt[bk], 1);
                unsigned p = (unsigned)(bbase[bk] + idx);
                if (p < BCAP) gbuck[(size_t)bk * BCAP + p] = ((unsigned)d4.w << 16) | (unsigned)s4.w;
            }
        }
    }
}

// ---------- build: bucket -> slot CSR (LDS atomics only) + cnt + fused zd scale ----------
__global__ __launch_bounds__(256) void build_scale(const unsigned* __restrict__ gbuck,
                                                   const int* __restrict__ gbcnt,
                                                   const uint2* __restrict__ zs2,
                                                   int* __restrict__ cnt,
                                                   unsigned short* __restrict__ slot,
                                                   uint2* __restrict__ zd2) {
    __shared__ int c128[128];
    int b = blockIdx.x;
    if (threadIdx.x < 128) c128[threadIdx.x] = 0;
    __syncthreads();
    int m = gbcnt[b * GB_STR];
    if (m > BCAP) m = BCAP;
    const unsigned* bk = gbuck + (size_t)b * BCAP;
    for (int i = threadIdx.x; i < m; i += 256) {
        unsigned e = bk[i];
        int d7 = (int)(e >> 16) & 127;
        int pos = atomicAdd(&c128[d7], 1);
        if (pos < SLOTS)
            slot[((size_t)((b << 7) + d7)) * SLOTS + pos] = (unsigned short)(e & 0xFFFFu);
    }
    __syncthreads();
    int n0 = b << 7;
    if (threadIdx.x < 128) {
        int n = n0 + threadIdx.x;
        if (n < N_NODES) cnt[n] = c128[threadIdx.x];
    }
    // fused scale: zd[n] = bf16( rsqrt(cnt[n]+1) * zs[n] ) for this block's 128 rows
    for (int i = threadIdx.x; i < 128 * 10; i += 256) {
        int r = i / 10;
        int n = n0 + r;
        if (n < N_NODES) {
            int k = i - r * 10;
            float dn = rsqrtf((float)(c128[r] + 1));
            float4 f = unpack_bf16x4(zs2[(size_t)n * 10 + k]);
            uint2 p;
            p.x = pack_bf16x2(dn * f.x, dn * f.y);
            p.y = pack_bf16x2(dn * f.z, dn * f.w);
            zd2[(size_t)n * 10 + k] = p;
        }
    }
}

// ---------- hop1 (40-dim): 6 nodes/wave, 10 lanes x uint2, pure adds, 8-deep ----------
// v1[n] = dn^2 * ( zd[n] + sum_s zd[s] )   (zd pre-scaled by dinv)
__global__ __launch_bounds__(256) void hop_all(const uint2* __restrict__ zd2,
                                               uint2* __restrict__ v12,
                                               const unsigned short* __restrict__ slot,
                                               const int* __restrict__ cnt) {
    int lane = threadIdx.x & 63;
    int g = lane / 10;
    int k = lane - g * 10;
    int wv = threadIdx.x >> 6;
    int n = blockIdx.x * 24 + wv * 6 + g;
    if (g >= 6 || n >= N_NODES) return;
    int c = cnt[n];
    int m = (c < SLOTS) ? c : SLOTS;
    float s = 1.0f / (float)(c + 1);       // dinv^2
    float4 accA = unpack_bf16x4(zd2[n * 10 + k]);   // self (already dinv-scaled)
    float4 accB; accB.x = accB.y = accB.z = accB.w = 0.0f;
    int base = n * SLOTS;
    int j = 0;
    for (; j + 7 < m; j += 8) {            // 8 independent gathers in flight
        unsigned ss0 = *(const unsigned*)&slot[base + j];
        unsigned ss1 = *(const unsigned*)&slot[base + j + 2];
        unsigned ss2 = *(const unsigned*)&slot[base + j + 4];
        unsigned ss3 = *(const unsigned*)&slot[base + j + 6];
        float4 f0 = unpack_bf16x4(zd2[(int)(ss0 & 0xFFFFu) * 10 + k]);
        float4 f1 = unpack_bf16x4(zd2[(int)(ss0 >> 16) * 10 + k]);
        float4 f2 = unpack_bf16x4(zd2[(int)(ss1 & 0xFFFFu) * 10 + k]);
        float4 f3 = unpack_bf16x4(zd2[(int)(ss1 >> 16) * 10 + k]);
        float4 f4 = unpack_bf16x4(zd2[(int)(ss2 & 0xFFFFu) * 10 + k]);
        float4 f5 = unpack_bf16x4(zd2[(int)(ss2 >> 16) * 10 + k]);
        float4 f6 = unpack_bf16x4(zd2[(int)(ss3 & 0xFFFFu) * 10 + k]);
        float4 f7 = unpack_bf16x4(zd2[(int)(ss3 >> 16) * 10 + k]);
        accA.x += (f0.x + f1.x) + (f4.x + f5.x);
        accA.y += (f0.y + f1.y) + (f4.y + f5.y);
        accA.z += (f0.z + f1.z) + (f4.z + f5.z);
        accA.w += (f0.w + f1.w) + (f4.w + f5.w);
        accB.x += (f2.x + f3.x) + (f6.x + f7.x);
        accB.y += (f2.y + f3.y) + (f6.y + f7.y);
        accB.z += (f2.z + f3.z) + (f6.z + f7.z);
        accB.w += (f2.w + f3.w) + (f6.w + f7.w);
    }
    for (; j + 1 < m; j += 2) {
        unsigned ss0 = *(const unsigned*)&slot[base + j];
        float4 f0 = unpack_bf16x4(zd2[(int)(ss0 & 0xFFFFu) * 10 + k]);
        float4 f1 = unpack_bf16x4(zd2[(int)(ss0 >> 16) * 10 + k]);
        accA.x += f0.x + f1.x;  accA.y += f0.y + f1.y;
        accA.z += f0.z + f1.z;  accA.w += f0.w + f1.w;
    }
    if (j < m) {
        float4 f0 = unpack_bf16x4(zd2[(int)slot[base + j] * 10 + k]);
        accB.x += f0.x; accB.y += f0.y; accB.z += f0.z; accB.w += f0.w;
    }
    uint2 p;
    p.x = pack_bf16x2(s * (accA.x + accB.x), s * (accA.y + accB.y));
    p.y = pack_bf16x2(s * (accA.z + accB.z), s * (accA.w + accB.w));
    v12[n * 10 + k] = p;
}

// ---------- fused hop2(rep) + bias + log_softmax + scatter to members ----------
__global__ __launch_bounds__(256) void rep_scatter(const unsigned* __restrict__ v1,
                                                   const unsigned short* __restrict__ slot,
                                                   const int* __restrict__ cnt,
                                                   const int* __restrict__ ccnt,
                                                   const unsigned short* __restrict__ cinv,
                                                   const int* __restrict__ rep_idx,
                                                   const float2* __restrict__ b2,
                                                   float2* __restrict__ out2) {
    int lane = threadIdx.x & 63;
    int wv = threadIdx.x >> 6;
    int c = blockIdx.x * 4 + wv;
    if (c >= N_CLUST) return;
    int n = rep_idx[c];
    int cn = cnt[n];
    int m = (cn < SLOTS) ? cn : SLOTS;
    float dn = rsqrtf((float)(cn + 1));
    int g = lane / 20;
    int k = lane - g * 20;
    float2 acc; acc.x = 0.0f; acc.y = 0.0f;
    if (g == 0) acc = unpack_bf16x2(v1[n * 20 + k]);   // self
    if (g < 3) {
        int base = n * SLOTS;
        for (int j = g; j < m; j += 3) {
            float2 f = unpack_bf16x2(v1[(int)slot[base + j] * 20 + k]);
            acc.x += f.x; acc.y += f.y;
        }
    }
    float t1x = __shfl(acc.x, lane + 20), t1y = __shfl(acc.y, lane + 20);
    float t2x = __shfl(acc.x, lane + 40), t2y = __shfl(acc.y, lane + 40);
    bool act = (lane < 20);
    float2 h; h.x = 0.0f; h.y = 0.0f;
    if (act) {
        float2 bb = b2[k];
        h.x = dn * (acc.x + t1x + t2x) + bb.x;
        h.y = dn * (acc.y + t1y + t2y) + bb.y;
    }
    float mx = act ? fmaxf(h.x, h.y) : -INFINITY;
    #pragma unroll
    for (int off = 32; off; off >>= 1) mx = fmaxf(mx, __shfl_xor(mx, off));
    float e = act ? (expf(h.x - mx) + expf(h.y - mx)) : 0.0f;
    #pragma unroll
    for (int off = 32; off; off >>= 1) e += __shfl_xor(e, off);
    float lg = mx + logf(e);
    float2 o; o.x = h.x - lg; o.y = h.y - lg;
    // scatter to all member nodes
    int mc = ccnt[c];
    if (mc > CSLOT) mc = CSLOT;
    const unsigned short* mem = cinv + c * CSLOT;
    for (int idx = 0; idx < mc; idx++) {
        int node = (int)mem[idx];
        if (act) out2[(size_t)node * 20 + k] = o;
    }
}

extern "C" void kernel_launch(void* const* d_in, const int* in_sizes, int n_in,
                              void* d_out, int out_size, void* d_ws, size_t ws_size,
                              hipStream_t stream) {
    const float* x    = (const float*)d_in[0];
    const int*   esrc = (const int*)d_in[1];
    const int*   edst = ((const int*)d_in[1]) + N_EDGES;
    const int*   cidx = (const int*)d_in[2];
    const int*   ridx = (const int*)d_in[3];
    const float* W    = (const float*)d_in[4];
    const float* b    = (const float*)d_in[5];
    float* out = (float*)d_out;

    char* ws = (char*)d_ws;
    size_t off = 0;
    auto alloc = [&](size_t bytes) { char* p = ws + off; off += (bytes + 255) & ~size_t(255); return p; };
    int*            cnt   = (int*)alloc((N_NODES + N_CLUST + NBKT * GB_STR) * 4);
    int*            ccnt  = cnt + N_NODES;
    int*            gbcnt = ccnt + N_CLUST;
    unsigned short* slot  = (unsigned short*)alloc((size_t)N_NODES * SLOTS * 2);  // 6.4 MB
    unsigned short* zs    = (unsigned short*)alloc((size_t)N_NODES * NOUT * 2);   // 4 MB
    unsigned short* zd    = (unsigned short*)alloc((size_t)N_NODES * NOUT * 2);   // 4 MB
    unsigned*       v1    = (unsigned*)alloc((size_t)N_NODES * (NOUT / 2) * 4);   // 4 MB
    unsigned short* cinv  = (unsigned short*)alloc((size_t)N_CLUST * CSLOT * 2);  // 640 KB
    unsigned*       gbuck = (unsigned*)alloc((size_t)NBKT * BCAP * 4);            // 4 MB
    (void)ws_size; (void)in_sizes; (void)n_in; (void)out_size;

    // cnt is fully rewritten by build_scale; only ccnt + gbcnt need zeroing
    hipMemsetAsync(ccnt, 0, (N_CLUST + NBKT * GB_STR) * 4, stream);

    fused_A<<<GRID_A, 256, 0, stream>>>(x, esrc, edst, cidx, W,
                                        ccnt, zs, cinv, gbcnt, gbuck);
    build_scale<<<NBKT, 256, 0, stream>>>(gbuck, gbcnt, (const uint2*)zs,
                                          cnt, slot, (uint2*)zd);
    hop_all<<<(N_NODES + 23) / 24, 256, 0, stream>>>((const uint2*)zd, (uint2*)v1,
                                                     slot, cnt);
    rep_scatter<<<(N_CLUST + 3) / 4, 256, 0, stream>>>((const unsigned*)v1, slot, cnt,
                                                       ccnt, cinv, ridx,
                                                       (const float2*)b, (float2*)out);
}